// Round 7
// baseline (253.983 us; speedup 1.0000x reference)
//
#include <hip/hip_runtime.h>
#include <hip/hip_bf16.h>

// PatchConv2d: out[b,o,h,w] = conv3x3(x,kernel) + 0.1*(h+w)*patch_sum[b,h,w] + bias[o]
// x:(16,64,128,128) f32, kernel:(128,64,3,3) f32, bias:(128,) f32 -> out(16,128,128,128) f32
//
// R10: back to the clean one-barrier R7 structure, tile quartered for
//      occupancy. Block = 1 output row x 64 w, 256 thr, fused staging.
//      LDS 26.7 KB -> 6 blocks/CU (R7 had 3, R9 had 2); grid 4096 = 16
//      queued/CU so inter-block overlap hides staging latency (the rolling
//      intra-block pipeline of R8/R9 is reverted -- it only bought scratch
//      spill, +44 MB HBM writes). No register arrays live across MFMA.
//      Staging: 48 coalesced dwords/thread + 384-lane halo pass with
//      wave-shuffle f32 column sums (patch_sum stays fp32-exact).
//      MFMA: 4 waves (2 m x 2 oc), acc[2][4]=32 VGPR, 144 MFMA/wave,
//      proven XOR swizzle (0 conflicts measured in R7/R9).

typedef __attribute__((ext_vector_type(8))) short short8;
typedef __attribute__((ext_vector_type(4))) float f32x4;

#define B_COEF 0.1f
constexpr int CI = 64, CO = 128, H = 128, W = 128;
constexpr int XPAD = 72;  // fallback-path LDS stride

static __device__ inline short bf16s(float v) {
    __hip_bfloat16 b = __float2bfloat16(v);
    return *reinterpret_cast<short*>(&b);
}

// barrier that does NOT drain vmcnt (ds ops flushed; global loads/stores fly)
static __device__ inline void bar_lgkm() {
    asm volatile("s_waitcnt lgkmcnt(0)" ::: "memory");
    __builtin_amdgcn_s_barrier();
    asm volatile("" ::: "memory");
}

// ============================ fast path ====================================

// kernel f32 [oc][ci][3][3] -> bf16 wq[tap][kc][oc][32] (ci = kc*32+j)
__global__ void prep_wq(const float* __restrict__ wgt, __hip_bfloat16* __restrict__ wq) {
    int idx = blockIdx.x * 256 + threadIdx.x;  // 9*128*64 = 73728
    if (idx < 9 * CO * CI) {
        int tap = idx >> 13;
        int rem = idx & 8191;
        int oc = rem >> 6, ci = rem & 63;
        int kc = ci >> 5, j = ci & 31;
        wq[(((tap * 2 + kc) * CO + oc) << 5) + j] =
            __float2bfloat16(wgt[(oc * CI + ci) * 9 + tap]);
    }
}

__global__ __launch_bounds__(256, 5)
void conv_fused(const float* __restrict__ x,
                const __hip_bfloat16* __restrict__ wq,
                const float* __restrict__ bias,
                float* __restrict__ out) {
    __shared__ __hip_bfloat16 xrow[3][66 * 64];  // 25,344 B (slots 0..65)
    __shared__ float psum[256];
    __shared__ float ssumL[66];
    __shared__ float Shalo[8];

    const int tid = threadIdx.x, bx = blockIdx.x, b = blockIdx.y;
    // XCD-coherent: u bijective in [0,256); xcd = bx&7 owns h in [16*xcd,+16)
    const int u = ((bx & 7) << 5) | (bx >> 3);
    const int h = u >> 1, w0 = (u & 1) * 64;
    const int lane = tid & 63, waveid = tid >> 6;
    const int lo16 = lane & 15, quad = lane >> 4;
    const int m0 = (waveid & 1) * 32;   // w slice (32 wide)
    const int n0 = (waveid >> 1) * 64;  // oc slice (64 wide)

    const float* xb = x + (size_t)b * CI * H * W;

    // ---- main staging: thread = (col c, ci-block cu). 48 coalesced dwords.
    const int c = tid & 63, cu = tid >> 6;
    const int slot = c + 1, ssw = slot & 7;
    float sacc = 0.0f;
#pragma unroll
    for (int r = 0; r < 3; ++r) {
        const int gh = h - 1 + r;
        float v[16];
        if ((unsigned)gh < (unsigned)H) {
            const float* px = xb + ((size_t)(cu * 16) * H + gh) * W + w0 + c;
#pragma unroll
            for (int j = 0; j < 16; ++j) v[j] = px[(size_t)j * H * W];
        } else {
#pragma unroll
            for (int j = 0; j < 16; ++j) v[j] = 0.0f;
        }
#pragma unroll
        for (int hf = 0; hf < 2; ++hf) {
            short8 pk;
#pragma unroll
            for (int j = 0; j < 8; ++j) {
                pk[j] = bf16s(v[hf * 8 + j]);
                sacc += v[hf * 8 + j];
            }
            const int unit = cu * 2 + hf;
            *(short8*)&xrow[r][slot * 64 + ((unit ^ ssw) * 8)] = pk;
        }
    }
    psum[tid] = sacc;

    // ---- halo columns (slots 0 and 65): 384 scalar loads, wave-reduced sums
#pragma unroll
    for (int it = 0; it < 2; ++it) {
        const int f = it * 256 + tid;
        if (f < 384) {
            const int wv = f >> 6, ci = f & 63;
            const int r = wv >> 1, hc = wv & 1;
            const int gh = h - 1 + r, gw = hc ? (w0 + 64) : (w0 - 1);
            float val = 0.0f;
            if ((unsigned)gh < (unsigned)H && (unsigned)gw < (unsigned)W)
                val = xb[((size_t)ci * H + gh) * W + gw];
            const int hs = hc ? 65 : 0;
            xrow[r][hs * 64 + (((ci >> 3) ^ (hs & 7)) * 8) + (ci & 7)] =
                __float2bfloat16(val);
            float s = val;
#pragma unroll
            for (int off = 1; off < 64; off <<= 1) s += __shfl_xor(s, off);
            if (ci == 0) Shalo[wv] = s;
        }
    }
    bar_lgkm();

    // ---- column-sum vector (3-row summed), incl. halo entries
    if (tid < 64)
        ssumL[tid + 1] = psum[tid] + psum[tid + 64] + psum[tid + 128] + psum[tid + 192];
    else if (tid == 64)
        ssumL[0] = Shalo[0] + Shalo[2] + Shalo[4];
    else if (tid == 65)
        ssumL[65] = Shalo[1] + Shalo[3] + Shalo[5];
    bar_lgkm();

    // ---- MFMA phase: wave = 32 w x 64 oc; acc[2][4] = 32 VGPR
    f32x4 acc[2][4] = {};
    __builtin_amdgcn_s_setprio(1);
#pragma unroll
    for (int kh = 0; kh < 3; ++kh) {
        const __hip_bfloat16* xs = &xrow[kh][0];
#pragma unroll
        for (int kw = 0; kw < 3; ++kw) {
            const int tap = kh * 3 + kw;
            short8 bq[2][4];
#pragma unroll
            for (int kc = 0; kc < 2; ++kc)
#pragma unroll
                for (int ni = 0; ni < 4; ++ni)
                    bq[kc][ni] = *(const short8*)(
                        wq + (((tap * 2 + kc) * CO + n0 + ni * 16 + lo16) << 5) + quad * 8);
#pragma unroll
            for (int kc = 0; kc < 2; ++kc) {
                short8 af[2];
#pragma unroll
                for (int mi = 0; mi < 2; ++mi) {
                    const int sl = m0 + mi * 16 + lo16 + kw;  // 0..65
                    af[mi] = *(const short8*)
                        &xs[sl * 64 + (((kc * 4 + quad) ^ (sl & 7)) * 8)];
                }
#pragma unroll
                for (int mi = 0; mi < 2; ++mi)
#pragma unroll
                    for (int ni = 0; ni < 4; ++ni)
                        acc[mi][ni] = __builtin_amdgcn_mfma_f32_16x16x32_bf16(
                            af[mi], bq[kc][ni], acc[mi][ni], 0, 0, 0);
            }
        }
    }
    __builtin_amdgcn_s_setprio(0);

    // ---- epilogue: + 0.1*(h+w)*patch_sum + bias; float4 stores
#pragma unroll
    for (int mi = 0; mi < 2; ++mi) {
        const int wbase = m0 + mi * 16 + quad * 4;  // local w
        float cs[6];
#pragma unroll
        for (int t = 0; t < 6; ++t) cs[t] = ssumL[wbase + t];
        float ps[4], cf[4];
#pragma unroll
        for (int t = 0; t < 4; ++t) {
            ps[t] = cs[t] + cs[t + 1] + cs[t + 2];
            cf[t] = B_COEF * (float)(h + w0 + wbase + t);
        }
#pragma unroll
        for (int ni = 0; ni < 4; ++ni) {
            const int oc = n0 + ni * 16 + lo16;
            const float bv = bias[oc];
            f32x4 v = acc[mi][ni];
#pragma unroll
            for (int t = 0; t < 4; ++t) v[t] = v[t] + cf[t] * ps[t] + bv;
            *(f32x4*)(out + (((size_t)b * CO + oc) * H + h) * W + w0 + wbase) = v;
        }
    }
}

// ===================== fallback path (R2, needs only 147 KB ws) ============

constexpr int WPAD = 72;

__global__ void prep_w_fb(const float* __restrict__ wgt, __hip_bfloat16* __restrict__ wt) {
    int idx = blockIdx.x * 256 + threadIdx.x;
    if (idx < 9 * CO * CI) {
        int tap = idx / (CO * CI);
        int rem = idx - tap * (CO * CI);
        int oc = rem >> 6, ci = rem & 63;
        wt[idx] = __float2bfloat16(wgt[(oc * CI + ci) * 9 + tap]);
    }
}

__global__ __launch_bounds__(256, 2)
void conv_fb(const float* __restrict__ x, const __hip_bfloat16* __restrict__ wt,
             const float* __restrict__ bias, float* __restrict__ out) {
    __shared__ __hip_bfloat16 xrow[130 * XPAD];
    __shared__ __hip_bfloat16 wlds[CO * WPAD];
    __shared__ float colsum[132];

    const int tid = threadIdx.x;
    const int h = blockIdx.x, b = blockIdx.y;
    const int lane = tid & 63, waveid = tid >> 6;
    const int lo16 = lane & 15, quad = lane >> 4;
    const int m0 = (waveid & 1) * 64, n0 = (waveid >> 1) * 64;

    f32x4 acc[4][4] = {};
    if (tid < 132) colsum[tid] = 0.0f;
    const float* xb = x + (size_t)b * CI * H * W;

    const int w16 = tid & 15, cipl = (tid >> 4) & 3, rest0 = tid >> 6;

    for (int kh = 0; kh < 3; ++kh) {
        const int gh = h - 1 + kh;
        __syncthreads();
        for (int it = 0; it < 18; ++it) {
            int rest = rest0 + it * 4;
            int whi = rest % 9, ciph = rest / 9;
            int w = whi * 16 + w16;
            int ci0 = (ciph * 4 + cipl) * 2;
            int gw = w - 1;
            float x0 = 0.0f, x1 = 0.0f;
            if (w < 130 && gw >= 0 && gw < W && gh >= 0 && gh < H) {
                const float* p = xb + (size_t)ci0 * (H * W) + gh * W + gw;
                x0 = p[0];
                x1 = p[H * W];
            }
            if (w < 130) {
                __hip_bfloat162 pk;
                pk.x = __float2bfloat16(x0);
                pk.y = __float2bfloat16(x1);
                *(__hip_bfloat162*)&xrow[w * XPAD + ci0] = pk;
            }
            float cs = x0 + x1;
            cs += __shfl_xor(cs, 16);
            cs += __shfl_xor(cs, 32);
            if (quad == 0 && w < 130) atomicAdd(&colsum[w], cs);
        }
        for (int kw = 0; kw < 3; ++kw) {
            __syncthreads();
            {
                const __hip_bfloat16* wtap = wt + (kh * 3 + kw) * (CO * CI);
#pragma unroll
                for (int it = 0; it < 4; ++it) {
                    int j = tid + it * 256;
                    int oc = j >> 3, ch = (j & 7) * 8;
                    short8 v = *(const short8*)(wtap + oc * CI + ch);
                    *(short8*)&wlds[oc * WPAD + ch] = v;
                }
            }
            __syncthreads();
#pragma unroll
            for (int kc = 0; kc < 2; ++kc) {
                const int krow = kc * 32 + quad * 8;
                short8 af[4], bf[4];
#pragma unroll
                for (int mi = 0; mi < 4; ++mi)
                    af[mi] = *(const short8*)&xrow[(m0 + mi * 16 + lo16 + kw) * XPAD + krow];
#pragma unroll
                for (int ni = 0; ni < 4; ++ni)
                    bf[ni] = *(const short8*)&wlds[(n0 + ni * 16 + lo16) * WPAD + krow];
#pragma unroll
                for (int mi = 0; mi < 4; ++mi)
#pragma unroll
                    for (int ni = 0; ni < 4; ++ni)
                        acc[mi][ni] = __builtin_amdgcn_mfma_f32_16x16x32_bf16(
                            af[mi], bf[ni], acc[mi][ni], 0, 0, 0);
            }
        }
    }
    __syncthreads();
#pragma unroll
    for (int mi = 0; mi < 4; ++mi) {
        const int wbase = m0 + mi * 16 + quad * 4;
        float cs[6];
#pragma unroll
        for (int r = 0; r < 6; ++r) cs[r] = colsum[wbase + r];
        float ps[4], cf[4];
#pragma unroll
        for (int r = 0; r < 4; ++r) {
            ps[r] = cs[r] + cs[r + 1] + cs[r + 2];
            cf[r] = B_COEF * (float)(h + wbase + r);
        }
#pragma unroll
        for (int ni = 0; ni < 4; ++ni) {
            const int oc = n0 + ni * 16 + lo16;
            const float bv = bias[oc];
            f32x4 v = acc[mi][ni];
#pragma unroll
            for (int r = 0; r < 4; ++r) v[r] = v[r] + cf[r] * ps[r] + bv;
            *(f32x4*)(out + (((size_t)b * CO + oc) * H + h) * W + wbase) = v;
        }
    }
}

// ===========================================================================

extern "C" void kernel_launch(void* const* d_in, const int* in_sizes, int n_in,
                              void* d_out, int out_size, void* d_ws, size_t ws_size,
                              hipStream_t stream) {
    const float* x    = (const float*)d_in[0];
    const float* wgt  = (const float*)d_in[1];
    const float* bias = (const float*)d_in[2];
    float* out = (float*)d_out;

    const size_t WQ_BYTES = (size_t)9 * 2 * CO * 32 * 2;  // 147,456

    if (ws_size >= WQ_BYTES) {
        __hip_bfloat16* wq = (__hip_bfloat16*)d_ws;
        prep_wq<<<dim3(288), dim3(256), 0, stream>>>(wgt, wq);
        conv_fused<<<dim3(2 * H, 16), dim3(256), 0, stream>>>(x, wq, bias, out);
    } else {
        __hip_bfloat16* wt = (__hip_bfloat16*)d_ws;  // 147,456 B
        prep_w_fb<<<dim3(288), dim3(256), 0, stream>>>(wgt, wt);
        conv_fb<<<dim3(H, 16), dim3(256), 0, stream>>>(x, wt, bias, out);
    }
}

// Round 8
// 225.462 us; speedup vs baseline: 1.1265x; 1.1265x over previous
//
#include <hip/hip_runtime.h>
#include <hip/hip_bf16.h>

// PatchConv2d: out[b,o,h,w] = conv3x3(x,kernel) + 0.1*(h+w)*patch_sum[b,h,w] + bias[o]
// x:(16,64,128,128) f32, kernel:(128,64,3,3) f32, bias:(128,) f32 -> out(16,128,128,128) f32
//
// R11: R7 base (best measured fused variant, 99.8 us) + B-fragment software
//      pipeline. The 18 per-tap bq load-wait-use groups (L2 latency ~300cyc
//      each, exposed at 3 waves/SIMD) are converted to a ping-pong prefetch:
//      tap0's frags issue at kernel entry (fly under staging), tap t+1's
//      frags issue before tap t's MFMA cluster. Barriers are lgkm-only (no
//      vmcnt drain) so prefetches and epilogue stores cross them in flight.
//      Everything else is byte-identical to R7 (proven staging, swizzle,
//      epilogue). R10's occupancy experiment is reverted (falsified).

typedef __attribute__((ext_vector_type(8))) short short8;
typedef __attribute__((ext_vector_type(4))) float f32x4;

#define B_COEF 0.1f
constexpr int CI = 64, CO = 128, H = 128, W = 128;
constexpr int XPAD = 72;  // fallback-path LDS stride

static __device__ inline short bf16s(float v) {
    __hip_bfloat16 b = __float2bfloat16(v);
    return *reinterpret_cast<short*>(&b);
}

// barrier that does NOT drain vmcnt (ds ops flushed; global loads/stores fly)
static __device__ inline void bar_lgkm() {
    asm volatile("s_waitcnt lgkmcnt(0)" ::: "memory");
    __builtin_amdgcn_s_barrier();
    asm volatile("" ::: "memory");
}

// ============================ fast path ====================================

// kernel f32 [oc][ci][3][3] -> bf16 wq[tap][kc][oc][32] (ci = kc*32+j)
__global__ void prep_wq(const float* __restrict__ wgt, __hip_bfloat16* __restrict__ wq) {
    int idx = blockIdx.x * 256 + threadIdx.x;  // 9*128*64 = 73728
    if (idx < 9 * CO * CI) {
        int tap = idx >> 13;
        int rem = idx & 8191;
        int oc = rem >> 6, ci = rem & 63;
        int kc = ci >> 5, j = ci & 31;
        wq[(((tap * 2 + kc) * CO + oc) << 5) + j] =
            __float2bfloat16(wgt[(oc * CI + ci) * 9 + tap]);
    }
}

// One output row (full W) per block: fused NCHW->NHWC-bf16 staging + conv.
__global__ __launch_bounds__(256, 3)
void conv_fused(const float* __restrict__ x,
                const __hip_bfloat16* __restrict__ wq,
                const float* __restrict__ bias,
                float* __restrict__ out) {
    __shared__ __hip_bfloat16 xrow[3][130 * 64];  // 49,920 B, swizzled units
    __shared__ float psum[256];
    __shared__ float ssumL[130];

    const int tid = threadIdx.x, bx = blockIdx.x, b = blockIdx.y;
    // XCD-coherent remap: xcd = bx&7 owns h in [xcd*16, xcd*16+16)
    const int h = ((bx & 7) << 4) | (bx >> 3);
    const int lane = tid & 63, waveid = tid >> 6;
    const int lo16 = lane & 15, quad = lane >> 4;
    const int m0 = (waveid & 1) * 64, n0 = (waveid >> 1) * 64;

    // ---- tap-0 B-fragments: issued FIRST (oldest vmcnt slots; they complete
    //      for free underneath the staging loads)
    short8 bq[2][2][4];  // [pingpong][kc][ni]
#pragma unroll
    for (int kc = 0; kc < 2; ++kc)
#pragma unroll
        for (int ni = 0; ni < 4; ++ni)
            bq[0][kc][ni] = *(const short8*)(
                wq + ((kc * CO + n0 + ni * 16 + lo16) << 5) + quad * 8);

    // ---- zero the two always-pad halo columns (slots 0 and 129)
    if (tid < 48) {
        const int r = tid >> 4, s = ((tid >> 3) & 1) ? 129 : 0, u = tid & 7;
        short8 z = {0, 0, 0, 0, 0, 0, 0, 0};
        *(short8*)&xrow[r][s * 64 + ((u ^ (s & 7)) * 8)] = z;
    }

    // ---- staged transpose: thread = (w, ci-group-half); 12 iters of
    //      {8 coalesced dword loads, cvt+pack, 1 swizzled ds_write_b128}
    const int wl = tid & 127, cg0 = tid >> 7;
    const int wslot = wl + 1, wsw = wslot & 7;
    float sacc = 0.0f;
    const float* xb = x + (size_t)b * CI * H * W + wl;
#pragma unroll
    for (int p = 0; p < 4; ++p) {
        const int cg = cg0 + 2 * p;
#pragma unroll
        for (int r = 0; r < 3; ++r) {
            const int gh = h - 1 + r;
            short8 pk = {0, 0, 0, 0, 0, 0, 0, 0};
            if (gh >= 0 && gh < H) {
                const float* px = xb + ((size_t)(cg * 8) * H + gh) * W;
                float v[8];
#pragma unroll
                for (int j = 0; j < 8; ++j) v[j] = px[(size_t)j * H * W];
#pragma unroll
                for (int j = 0; j < 8; ++j) {
                    pk[j] = bf16s(v[j]);
                    sacc += v[j];
                }
            }
            *(short8*)&xrow[r][wslot * 64 + ((cg ^ wsw) * 8)] = pk;
        }
    }
    psum[tid] = sacc;
    bar_lgkm();

    // ---- column sums (patch_sum precursor, already 3-row summed)
    if (tid < 128) ssumL[tid + 1] = psum[tid] + psum[tid + 128];
    if (tid == 128) ssumL[0] = 0.0f;
    if (tid == 129) ssumL[129] = 0.0f;
    bar_lgkm();

    // ---- MFMA phase: tap-flattened loop, bq ping-pong prefetch
    f32x4 acc[4][4] = {};

    __builtin_amdgcn_s_setprio(1);
#pragma unroll
    for (int tap = 0; tap < 9; ++tap) {
        const int pp = tap & 1;
        // prefetch next tap's B-frags; MFMA below waits only on bq[pp]
        if (tap < 8) {
            const int tn = tap + 1;
#pragma unroll
            for (int kc = 0; kc < 2; ++kc)
#pragma unroll
                for (int ni = 0; ni < 4; ++ni)
                    bq[pp ^ 1][kc][ni] = *(const short8*)(
                        wq + (((tn * 2 + kc) * CO + n0 + ni * 16 + lo16) << 5) + quad * 8);
        }
        const int kh = tap / 3, kw = tap - kh * 3;
        const __hip_bfloat16* xs = &xrow[kh][0];
#pragma unroll
        for (int kc = 0; kc < 2; ++kc) {
            short8 af[4];
#pragma unroll
            for (int mi = 0; mi < 4; ++mi) {
                const int row = m0 + mi * 16 + lo16 + kw;
                af[mi] = *(const short8*)
                    &xs[row * 64 + (((kc * 4 + quad) ^ (row & 7)) * 8)];
            }
#pragma unroll
            for (int mi = 0; mi < 4; ++mi)
#pragma unroll
                for (int ni = 0; ni < 4; ++ni)
                    acc[mi][ni] = __builtin_amdgcn_mfma_f32_16x16x32_bf16(
                        af[mi], bq[pp][kc][ni], acc[mi][ni], 0, 0, 0);
        }
    }
    __builtin_amdgcn_s_setprio(0);

    // ---- epilogue: + 0.1*(h+w)*patch_sum + bias; float4 stores (fire & fly)
#pragma unroll
    for (int mi = 0; mi < 4; ++mi) {
        const int wbase = m0 + mi * 16 + quad * 4;
        float cs[6];
#pragma unroll
        for (int t = 0; t < 6; ++t) cs[t] = ssumL[wbase + t];
        float ps[4], cf[4];
#pragma unroll
        for (int t = 0; t < 4; ++t) {
            ps[t] = cs[t] + cs[t + 1] + cs[t + 2];
            cf[t] = B_COEF * (float)(h + wbase + t);
        }
#pragma unroll
        for (int ni = 0; ni < 4; ++ni) {
            const int oc = n0 + ni * 16 + lo16;
            const float bv = bias[oc];
            f32x4 v = acc[mi][ni];
#pragma unroll
            for (int t = 0; t < 4; ++t) v[t] = v[t] + cf[t] * ps[t] + bv;
            *(f32x4*)(out + (((size_t)b * CO + oc) * H + h) * W + wbase) = v;
        }
    }
}

// ===================== fallback path (R2, needs only 147 KB ws) ============

constexpr int WPAD = 72;

__global__ void prep_w_fb(const float* __restrict__ wgt, __hip_bfloat16* __restrict__ wt) {
    int idx = blockIdx.x * 256 + threadIdx.x;
    if (idx < 9 * CO * CI) {
        int tap = idx / (CO * CI);
        int rem = idx - tap * (CO * CI);
        int oc = rem >> 6, ci = rem & 63;
        wt[idx] = __float2bfloat16(wgt[(oc * CI + ci) * 9 + tap]);
    }
}

__global__ __launch_bounds__(256, 2)
void conv_fb(const float* __restrict__ x, const __hip_bfloat16* __restrict__ wt,
             const float* __restrict__ bias, float* __restrict__ out) {
    __shared__ __hip_bfloat16 xrow[130 * XPAD];
    __shared__ __hip_bfloat16 wlds[CO * WPAD];
    __shared__ float colsum[132];

    const int tid = threadIdx.x;
    const int h = blockIdx.x, b = blockIdx.y;
    const int lane = tid & 63, waveid = tid >> 6;
    const int lo16 = lane & 15, quad = lane >> 4;
    const int m0 = (waveid & 1) * 64, n0 = (waveid >> 1) * 64;

    f32x4 acc[4][4] = {};
    if (tid < 132) colsum[tid] = 0.0f;
    const float* xb = x + (size_t)b * CI * H * W;

    const int w16 = tid & 15, cipl = (tid >> 4) & 3, rest0 = tid >> 6;

    for (int kh = 0; kh < 3; ++kh) {
        const int gh = h - 1 + kh;
        __syncthreads();
        for (int it = 0; it < 18; ++it) {
            int rest = rest0 + it * 4;
            int whi = rest % 9, ciph = rest / 9;
            int w = whi * 16 + w16;
            int ci0 = (ciph * 4 + cipl) * 2;
            int gw = w - 1;
            float x0 = 0.0f, x1 = 0.0f;
            if (w < 130 && gw >= 0 && gw < W && gh >= 0 && gh < H) {
                const float* p = xb + (size_t)ci0 * (H * W) + gh * W + gw;
                x0 = p[0];
                x1 = p[H * W];
            }
            if (w < 130) {
                __hip_bfloat162 pk;
                pk.x = __float2bfloat16(x0);
                pk.y = __float2bfloat16(x1);
                *(__hip_bfloat162*)&xrow[w * XPAD + ci0] = pk;
            }
            float cs = x0 + x1;
            cs += __shfl_xor(cs, 16);
            cs += __shfl_xor(cs, 32);
            if (quad == 0 && w < 130) atomicAdd(&colsum[w], cs);
        }
        for (int kw = 0; kw < 3; ++kw) {
            __syncthreads();
            {
                const __hip_bfloat16* wtap = wt + (kh * 3 + kw) * (CO * CI);
#pragma unroll
                for (int it = 0; it < 4; ++it) {
                    int j = tid + it * 256;
                    int oc = j >> 3, ch = (j & 7) * 8;
                    short8 v = *(const short8*)(wtap + oc * CI + ch);
                    *(short8*)&wlds[oc * WPAD + ch] = v;
                }
            }
            __syncthreads();
#pragma unroll
            for (int kc = 0; kc < 2; ++kc) {
                const int krow = kc * 32 + quad * 8;
                short8 af[4], bf[4];
#pragma unroll
                for (int mi = 0; mi < 4; ++mi)
                    af[mi] = *(const short8*)&xrow[(m0 + mi * 16 + lo16 + kw) * XPAD + krow];
#pragma unroll
                for (int ni = 0; ni < 4; ++ni)
                    bf[ni] = *(const short8*)&wlds[(n0 + ni * 16 + lo16) * WPAD + krow];
#pragma unroll
                for (int mi = 0; mi < 4; ++mi)
#pragma unroll
                    for (int ni = 0; ni < 4; ++ni)
                        acc[mi][ni] = __builtin_amdgcn_mfma_f32_16x16x32_bf16(
                            af[mi], bf[ni], acc[mi][ni], 0, 0, 0);
            }
        }
    }
    __syncthreads();
#pragma unroll
    for (int mi = 0; mi < 4; ++mi) {
        const int wbase = m0 + mi * 16 + quad * 4;
        float cs[6];
#pragma unroll
        for (int r = 0; r < 6; ++r) cs[r] = colsum[wbase + r];
        float ps[4], cf[4];
#pragma unroll
        for (int r = 0; r < 4; ++r) {
            ps[r] = cs[r] + cs[r + 1] + cs[r + 2];
            cf[r] = B_COEF * (float)(h + wbase + r);
        }
#pragma unroll
        for (int ni = 0; ni < 4; ++ni) {
            const int oc = n0 + ni * 16 + lo16;
            const float bv = bias[oc];
            f32x4 v = acc[mi][ni];
#pragma unroll
            for (int r = 0; r < 4; ++r) v[r] = v[r] + cf[r] * ps[r] + bv;
            *(f32x4*)(out + (((size_t)b * CO + oc) * H + h) * W + wbase) = v;
        }
    }
}

// ===========================================================================

extern "C" void kernel_launch(void* const* d_in, const int* in_sizes, int n_in,
                              void* d_out, int out_size, void* d_ws, size_t ws_size,
                              hipStream_t stream) {
    const float* x    = (const float*)d_in[0];
    const float* wgt  = (const float*)d_in[1];
    const float* bias = (const float*)d_in[2];
    float* out = (float*)d_out;

    const size_t WQ_BYTES = (size_t)9 * 2 * CO * 32 * 2;  // 147,456

    if (ws_size >= WQ_BYTES) {
        __hip_bfloat16* wq = (__hip_bfloat16*)d_ws;
        prep_wq<<<dim3(288), dim3(256), 0, stream>>>(wgt, wq);
        conv_fused<<<dim3(H, 16), dim3(256), 0, stream>>>(x, wq, bias, out);
    } else {
        __hip_bfloat16* wt = (__hip_bfloat16*)d_ws;  // 147,456 B
        prep_w_fb<<<dim3(288), dim3(256), 0, stream>>>(wgt, wt);
        conv_fb<<<dim3(H, 16), dim3(256), 0, stream>>>(x, wt, bias, out);
    }
}